// Round 1
// baseline (1425.637 us; speedup 1.0000x reference)
//
#include <hip/hip_runtime.h>
#include <hip/hip_bf16.h>

typedef __attribute__((ext_vector_type(8))) short short8;
typedef __attribute__((ext_vector_type(4))) float f32x4;

#define CI_STRIDE 25088  // 8*3136, stride between ci planes within one (b,t) slice

__device__ inline unsigned pk2_bf16(float a, float b){
  union {float f; unsigned u;} x, y;
  x.f = a; y.f = b;
  unsigned xa = x.u + 0x7fffu + ((x.u >> 16) & 1u);
  unsigned yb = y.u + 0x7fffu + ((y.u >> 16) & 1u);
  return (xa >> 16) | (yb & 0xffff0000u);
}

// ---------------- K0: repack W -> Wb[kxy][co][ci] (bf16) + zero stats ----------------
__global__ __launch_bounds__(256) void k_prep(const float* __restrict__ W,
                                              short* __restrict__ Wb,
                                              float* __restrict__ stats){
  if (blockIdx.x == 0){
    #pragma unroll
    for (int k = 0; k < 4; ++k) stats[threadIdx.x*4 + k] = 0.f;
  }
  int idx = blockIdx.x*256 + threadIdx.x;   // 589824 total, exact
  int kxy = idx >> 16;
  int r = idx & 65535;
  int co = r >> 8, ci = r & 255;
  float v = W[(size_t)(co*256 + ci)*9 + kxy];
  union {float f; unsigned u;} uu; uu.f = v;
  unsigned q = uu.u + 0x7fffu + ((uu.u >> 16) & 1u);
  Wb[idx] = (short)(q >> 16);
}

// ---------------- K1: spatial mean  feat[b,c,t,:,:] -> x0[b,c,t] ----------------
__global__ __launch_bounds__(256) void k_mean(const float* __restrict__ feat,
                                              float* __restrict__ x0){
  int id = blockIdx.x;  // (b*256+c)*8+t
  const f32x4* src = (const f32x4*)(feat + (size_t)id*3136);
  float s = 0.f;
  for (int i = threadIdx.x; i < 784; i += 256){
    f32x4 v = src[i];
    s += (v.x + v.y) + (v.z + v.w);
  }
  for (int o = 32; o; o >>= 1) s += __shfl_down(s, o, 64);
  __shared__ float wsum[4];
  int lane = threadIdx.x & 63, w = threadIdx.x >> 6;
  if (!lane) wsum[w] = s;
  __syncthreads();
  if (threadIdx.x == 0) x0[id] = (wsum[0]+wsum[1]+wsum[2]+wsum[3]) * (1.f/3136.f);
}

// ---------------- K2: routing function (per-batch block) ----------------
__global__ __launch_bounds__(256) void k_route(
    const float* __restrict__ x0, const float* __restrict__ a_w, const float* __restrict__ a_b,
    const float* __restrict__ norm_w, const float* __restrict__ norm_b,
    const float* __restrict__ normt_w, const float* __restrict__ normt_b,
    const float* __restrict__ qkv_w, const float* __restrict__ qkv_b,
    const float* __restrict__ ao_w, const float* __restrict__ ao_b,
    const float* __restrict__ b_w, const float* __restrict__ bb_w,
    const float* __restrict__ bias_p,
    float* __restrict__ wa, float* __restrict__ bbt){
  __shared__ float x0l[2048];
  __shared__ float x1[512];
  __shared__ float x2[512];
  __shared__ float xn[512];
  __shared__ float qkvl[1536];
  __shared__ float att[64];
  __shared__ float ol[512];
  __shared__ float x3[512];
  __shared__ float mu8[8], rs8[8];
  int b = blockIdx.x, tid = threadIdx.x;

  for (int i = tid; i < 2048; i += 256) x0l[i] = x0[b*2048 + i];
  __syncthreads();

  // conv 'a': x1[cr,t]
  for (int o = tid; o < 512; o += 256){
    int cr = o >> 3, t = o & 7;
    float acc = a_b[cr];
    const float* aw = a_w + cr*768;
    const float* xc = x0l + t;
    for (int c = 0; c < 256; ++c){
      float s = aw[c*3+1] * xc[c*8];
      if (t > 0) s += aw[c*3]   * xc[c*8 - 1];
      if (t < 7) s += aw[c*3+2] * xc[c*8 + 1];
      acc += s;
    }
    x1[o] = acc;
  }
  __syncthreads();

  // LN over channels + qGELU
  if (tid < 8){
    float s = 0.f, q = 0.f;
    for (int cr = 0; cr < 64; ++cr){ float v = x1[cr*8 + tid]; s += v; q += v*v; }
    float mu = s * (1.f/64.f);
    float var = q * (1.f/64.f) - mu*mu;
    mu8[tid] = mu; rs8[tid] = rsqrtf(var + 1e-6f);
  }
  __syncthreads();
  for (int o = tid; o < 512; o += 256){
    int cr = o >> 3, t = o & 7;
    float v = (x1[o] - mu8[t]) * rs8[t] * norm_w[cr] + norm_b[cr];
    x2[o] = v * (1.f / (1.f + __expf(-1.702f * v)));
  }
  __syncthreads();

  // LN_t
  if (tid < 8){
    float s = 0.f, q = 0.f;
    for (int cr = 0; cr < 64; ++cr){ float v = x2[cr*8 + tid]; s += v; q += v*v; }
    float mu = s * (1.f/64.f);
    float var = q * (1.f/64.f) - mu*mu;
    mu8[tid] = mu; rs8[tid] = rsqrtf(var + 1e-6f);
  }
  __syncthreads();
  for (int o = tid; o < 512; o += 256){
    int cr = o >> 3, t = o & 7;
    xn[o] = (x2[o] - mu8[t]) * rs8[t] * normt_w[cr] + normt_b[cr];
  }
  __syncthreads();

  // qkv: [192,64] @ xn
  for (int o = tid; o < 1536; o += 256){
    int oc = o >> 3, t = o & 7;
    float acc = qkv_b[oc];
    const float* qw = qkv_w + oc*64;
    for (int c = 0; c < 64; ++c) acc += qw[c] * xn[c*8 + t];
    qkvl[o] = acc;
  }
  __syncthreads();

  // attention scores (1 head, t=8), scale = 64^-0.5 = 0.125
  if (tid < 64){
    int tq = tid >> 3, tk = tid & 7;
    float s = 0.f;
    for (int d = 0; d < 64; ++d) s += qkvl[d*8 + tq] * qkvl[(64+d)*8 + tk];
    att[tid] = s * 0.125f;
  }
  __syncthreads();
  if (tid < 8){
    float m = att[tid*8];
    for (int k = 1; k < 8; ++k) m = fmaxf(m, att[tid*8 + k]);
    float e[8]; float s = 0.f;
    for (int k = 0; k < 8; ++k){ e[k] = __expf(att[tid*8 + k] - m); s += e[k]; }
    float inv = 1.f / s;
    for (int k = 0; k < 8; ++k) att[tid*8 + k] = e[k] * inv;
  }
  __syncthreads();
  // o = attn @ v  -> ol[tq*64+d]
  for (int o = tid; o < 512; o += 256){
    int tq = o >> 6, d = o & 63;
    float acc = 0.f;
    for (int k = 0; k < 8; ++k) acc += att[tq*8 + k] * qkvl[(128+d)*8 + k];
    ol[o] = acc;
  }
  __syncthreads();
  // proj + residual
  for (int o = tid; o < 512; o += 256){
    int cr = o >> 3, t = o & 7;
    float acc = ao_b[cr];
    const float* aw = ao_w + cr*64;
    for (int d = 0; d < 64; ++d) acc += aw[d] * ol[t*64 + d];
    x3[o] = x2[o] + acc;
  }
  __syncthreads();
  // w_alpha / bias_bt
  for (int o = tid; o < 2048; o += 256){
    int c = o >> 3, t = o & 7;
    float wacc = 0.f, bacc = 0.f;
    const float* xc = x3 + t;
    const float* bw  = b_w  + c*192;
    const float* bw2 = bb_w + c*192;
    for (int cr = 0; cr < 64; ++cr){
      float xm = xc[cr*8];
      wacc += bw[cr*3+1]*xm;  bacc += bw2[cr*3+1]*xm;
      if (t > 0){ float xl = xc[cr*8-1]; wacc += bw[cr*3]*xl;   bacc += bw2[cr*3]*xl; }
      if (t < 7){ float xr = xc[cr*8+1]; wacc += bw[cr*3+2]*xr; bacc += bw2[cr*3+2]*xr; }
    }
    wa[b*2048 + o] = wacc;
    bbt[(b*8 + t)*256 + c] = bacc * bias_p[c];
  }
}

// ---------------- K3: calibrated 3x3 conv via implicit-GEMM bf16 MFMA ----------------
// workgroup = one (image bt, output row y); 4 waves; 256co x 56pos tile; K = ci(256) x 3 x 3
__global__ __launch_bounds__(256) void k_conv(const float* __restrict__ feat,
                                              const short* __restrict__ Wb,
                                              const float* __restrict__ wa,
                                              const float* __restrict__ bbt,
                                              float* __restrict__ out){
  __shared__ short buf[2][58*256];   // [col][ci], XOR-swizzled, 29696 B each
  __shared__ float wal[256];

  int bid = blockIdx.x;
  int swz = (bid & 7)*448 + (bid >> 3);   // bijective XCD swizzle (3584 = 8*448)
  int img = swz / 56, y = swz - img*56;
  int b = img >> 3, t = img & 7;
  int tid = threadIdx.x;
  int lane = tid & 63, wave = tid >> 6;
  int arow = lane & 15, agrp = lane >> 4;

  wal[tid] = wa[(b*256 + tid)*8 + t];
  __syncthreads();

  const float* fb = feat + (size_t)b*256*8*3136 + (size_t)t*3136;

  f32x4 acc[4][4] = {};

  auto stage = [&](int bi, int ky){
    short* dst = buf[bi];
    int yin = y + ky - 1;
    bool rowok = (yin >= 0) && (yin < 56);
    const float* rsrc = fb + (size_t)yin*56;
    for (int i = tid; i < 128*58; i += 256){
      int ci2 = i / 58;
      int col = i - ci2*58;
      int ci = ci2 << 1;
      float v0 = 0.f, v1 = 0.f;
      int x = col - 1;
      if (rowok && (unsigned)x < 56u){
        v0 = rsrc[(size_t)ci*CI_STRIDE + x]     * wal[ci];
        v1 = rsrc[(size_t)(ci+1)*CI_STRIDE + x] * wal[ci+1];
      }
      unsigned p = pk2_bf16(v0, v1);
      int addr = ((col << 9) | (ci << 1)) ^ ((col & 7) << 4);
      *(unsigned*)((char*)dst + addr) = p;
    }
  };

  auto compute = [&](int bi, int ky){
    const short* sbuf = buf[bi];
    for (int kx = 0; kx < 3; ++kx){
      const short* wsl = Wb + (size_t)(ky*3 + kx)*65536 + (wave*64 + arow)*256 + (agrp << 3);
      for (int cs = 0; cs < 8; ++cs){
        int ci0 = (cs << 5) + (agrp << 3);
        short8 af[4], bfr[4];
        #pragma unroll
        for (int cf = 0; cf < 4; ++cf)
          af[cf] = *(const short8*)(wsl + cf*16*256 + (cs << 5));
        #pragma unroll
        for (int pf = 0; pf < 4; ++pf){
          int col = (pf << 4) + arow + kx;
          if (col > 57) col = 57;            // pf=3 pad lanes: any in-bounds data, discarded later
          int addr = ((col << 9) | (ci0 << 1)) ^ ((col & 7) << 4);
          bfr[pf] = *(const short8*)((const char*)sbuf + addr);
        }
        #pragma unroll
        for (int cf = 0; cf < 4; ++cf){
          #pragma unroll
          for (int pf = 0; pf < 4; ++pf)
            acc[cf][pf] = __builtin_amdgcn_mfma_f32_16x16x32_bf16(af[cf], bfr[pf], acc[cf][pf], 0, 0, 0);
        }
      }
    }
  };

  stage(0, 0);
  __syncthreads();
  stage(1, 1);        // prefetch next row while computing current
  compute(0, 0);
  __syncthreads();
  stage(0, 2);
  compute(1, 1);
  __syncthreads();
  compute(0, 2);

  // epilogue: D[row][col]: col = lane&15 (x within frag), row = (lane>>4)*4 + reg (co within frag)
  float* obase = out + (size_t)b*256*8*3136 + (size_t)t*3136 + y*56;
  const float* bb = bbt + (b*8 + t)*256;
  #pragma unroll
  for (int cf = 0; cf < 4; ++cf){
    int co0 = wave*64 + cf*16 + agrp*4;
    #pragma unroll
    for (int r = 0; r < 4; ++r){
      int co = co0 + r;
      float bias = bb[co];
      float* orow = obase + (size_t)co*CI_STRIDE;
      #pragma unroll
      for (int pf = 0; pf < 4; ++pf){
        int x = (pf << 4) + arow;
        if (x < 56) orow[x] = acc[cf][pf][r] + bias;
      }
    }
  }
}

// ---------------- K4: per-channel stats of out and its temporal 3-avgpool ----------------
__global__ __launch_bounds__(256) void k_stats(const float* __restrict__ out,
                                               float* __restrict__ stats){
  int bc = blockIdx.x;          // b*256 + c
  int c = bc & 255;
  const f32x4* base = (const f32x4*)(out + (size_t)bc*CI_STRIDE);
  float so = 0.f, ss = 0.f, sp = 0.f, sq = 0.f;
  const float inv3 = 1.f/3.f;
  for (int i = threadIdx.x; i < 784; i += 256){
    f32x4 v[8];
    #pragma unroll
    for (int t2 = 0; t2 < 8; ++t2) v[t2] = base[t2*784 + i];
    #pragma unroll
    for (int t2 = 0; t2 < 8; ++t2){
      f32x4 x = v[t2];
      so += (x.x + x.y) + (x.z + x.w);
      ss += (x.x*x.x + x.y*x.y) + (x.z*x.z + x.w*x.w);
    }
    #pragma unroll
    for (int t2 = 0; t2 < 8; ++t2){
      f32x4 s = v[t2];
      if (t2 > 0) s = s + v[t2-1];
      if (t2 < 7) s = s + v[t2+1];
      f32x4 a = s * inv3;
      sp += (a.x + a.y) + (a.z + a.w);
      sq += (a.x*a.x + a.y*a.y) + (a.z*a.z + a.w*a.w);
    }
  }
  for (int o = 32; o; o >>= 1){
    so += __shfl_down(so, o, 64); ss += __shfl_down(ss, o, 64);
    sp += __shfl_down(sp, o, 64); sq += __shfl_down(sq, o, 64);
  }
  __shared__ float red[4][4];
  int lane = threadIdx.x & 63, w = threadIdx.x >> 6;
  if (!lane){ red[w][0] = so; red[w][1] = ss; red[w][2] = sp; red[w][3] = sq; }
  __syncthreads();
  if (threadIdx.x < 4){
    float s = red[0][threadIdx.x] + red[1][threadIdx.x] + red[2][threadIdx.x] + red[3][threadIdx.x];
    atomicAdd(&stats[c*4 + threadIdx.x], s);
  }
}

// ---------------- K5: finalize per-channel BN scale/offset ----------------
__global__ void k_scale(const float* __restrict__ stats,
                        const float* __restrict__ ga, const float* __restrict__ ba_,
                        const float* __restrict__ gb, const float* __restrict__ bb_,
                        float* __restrict__ scale){
  int c = threadIdx.x;
  const float n = 200704.f;
  float mu_a = stats[c*4]   / n;
  float va   = stats[c*4+1] / n - mu_a*mu_a;
  float mu_p = stats[c*4+2] / n;
  float vp   = stats[c*4+3] / n - mu_p*mu_p;
  float ra = rsqrtf(va + 1e-5f) * ga[c];
  float rp = rsqrtf(vp + 1e-5f) * gb[c];
  scale[c*3]   = ra;
  scale[c*3+1] = rp;
  scale[c*3+2] = ba_[c] + bb_[c] - mu_a*ra - mu_p*rp;
}

// ---------------- K6: in-place normalize: out = bn_a(out) + bn_b(avgpool_t3(out)) ----------------
__global__ __launch_bounds__(256) void k_final(float* __restrict__ out,
                                               const float* __restrict__ scale){
  int bc = blockIdx.x;
  int c = bc & 255;
  float ra  = scale[c*3];
  float rp  = scale[c*3+1];
  float off = scale[c*3+2];
  f32x4* base = (f32x4*)(out + (size_t)bc*CI_STRIDE);
  const float inv3 = 1.f/3.f;
  for (int i = threadIdx.x; i < 784; i += 256){
    f32x4 v[8];
    #pragma unroll
    for (int t2 = 0; t2 < 8; ++t2) v[t2] = base[t2*784 + i];
    #pragma unroll
    for (int t2 = 0; t2 < 8; ++t2){
      f32x4 s = v[t2];
      if (t2 > 0) s = s + v[t2-1];
      if (t2 < 7) s = s + v[t2+1];
      f32x4 o = v[t2]*ra + (s*inv3)*rp + off;
      base[t2*784 + i] = o;
    }
  }
}

extern "C" void kernel_launch(void* const* d_in, const int* in_sizes, int n_in,
                              void* d_out, int out_size, void* d_ws, size_t ws_size,
                              hipStream_t stream){
  (void)in_sizes; (void)n_in; (void)out_size; (void)ws_size;
  const float* feat    = (const float*)d_in[0];
  const float* W       = (const float*)d_in[1];
  const float* bias_p  = (const float*)d_in[2];
  const float* a_w     = (const float*)d_in[3];
  const float* a_b     = (const float*)d_in[4];
  const float* norm_w  = (const float*)d_in[5];
  const float* norm_b  = (const float*)d_in[6];
  const float* normt_w = (const float*)d_in[7];
  const float* normt_b = (const float*)d_in[8];
  const float* qkv_w   = (const float*)d_in[9];
  const float* qkv_b   = (const float*)d_in[10];
  const float* ao_w    = (const float*)d_in[11];
  const float* ao_b    = (const float*)d_in[12];
  const float* b_w     = (const float*)d_in[13];
  const float* bb_w    = (const float*)d_in[14];
  const float* gamma_a = (const float*)d_in[15];
  const float* beta_a  = (const float*)d_in[16];
  const float* gamma_b = (const float*)d_in[17];
  const float* beta_b  = (const float*)d_in[18];
  float* out = (float*)d_out;

  char* ws = (char*)d_ws;
  short* Wb    = (short*)ws;                               // 1,179,648 B
  float* x0    = (float*)(ws + 1179648);                   // 65,536 B
  float* wa    = (float*)(ws + 1179648 + 65536);           // 65,536 B
  float* bbt   = (float*)(ws + 1179648 + 2*65536);         // 65,536 B
  float* stats = (float*)(ws + 1179648 + 3*65536);         // 4,096 B
  float* scale = (float*)(ws + 1179648 + 3*65536 + 4096);  // 3,072 B

  k_prep <<<2304, 256, 0, stream>>>(W, Wb, stats);
  k_mean <<<16384, 256, 0, stream>>>(feat, x0);
  k_route<<<8, 256, 0, stream>>>(x0, a_w, a_b, norm_w, norm_b, normt_w, normt_b,
                                 qkv_w, qkv_b, ao_w, ao_b, b_w, bb_w, bias_p, wa, bbt);
  k_conv <<<3584, 256, 0, stream>>>(feat, Wb, wa, bbt, out);
  k_stats<<<2048, 256, 0, stream>>>(out, stats);
  k_scale<<<1, 256, 0, stream>>>(stats, gamma_a, beta_a, gamma_b, beta_b, scale);
  k_final<<<2048, 256, 0, stream>>>(out, scale);
}

// Round 4
// 1271.342 us; speedup vs baseline: 1.1214x; 1.1214x over previous
//
#include <hip/hip_runtime.h>
#include <hip/hip_bf16.h>

typedef __attribute__((ext_vector_type(8))) short short8;
typedef __attribute__((ext_vector_type(4))) float f32x4;

#define CI_STRIDE 25088  // 8*3136, stride between ci planes within one (b,t) slice

__device__ inline unsigned pk2_bf16(float a, float b){
  union {float f; unsigned u;} x, y;
  x.f = a; y.f = b;
  unsigned xa = x.u + 0x7fffu + ((x.u >> 16) & 1u);
  unsigned yb = y.u + 0x7fffu + ((y.u >> 16) & 1u);
  return (xa >> 16) | (yb & 0xffff0000u);
}

#define GL2LDS16(g, l) __builtin_amdgcn_global_load_lds( \
    (const __attribute__((address_space(1))) void*)(g),  \
    (__attribute__((address_space(3))) void*)(l), 16, 0, 0)

// ---------------- K0: repack W -> Wb[kxy][co][ci] (bf16) + zero stats ----------------
__global__ __launch_bounds__(256) void k_prep(const float* __restrict__ W,
                                              short* __restrict__ Wb,
                                              float* __restrict__ stats){
  if (blockIdx.x == 0){
    #pragma unroll
    for (int k = 0; k < 4; ++k) stats[threadIdx.x*4 + k] = 0.f;
  }
  int idx = blockIdx.x*256 + threadIdx.x;   // 589824 total, exact
  int kxy = idx >> 16;
  int r = idx & 65535;
  int co = r >> 8, ci = r & 255;
  float v = W[(size_t)(co*256 + ci)*9 + kxy];
  union {float f; unsigned u;} uu; uu.f = v;
  unsigned q = uu.u + 0x7fffu + ((uu.u >> 16) & 1u);
  Wb[idx] = (short)(q >> 16);
}

// ---------------- K1: spatial mean  feat[b,c,t,:,:] -> x0[b,c,t] ----------------
__global__ __launch_bounds__(256) void k_mean(const float* __restrict__ feat,
                                              float* __restrict__ x0){
  int id = blockIdx.x;  // (b*256+c)*8+t
  const f32x4* src = (const f32x4*)(feat + (size_t)id*3136);
  float s = 0.f;
  for (int i = threadIdx.x; i < 784; i += 256){
    f32x4 v = src[i];
    s += (v.x + v.y) + (v.z + v.w);
  }
  for (int o = 32; o; o >>= 1) s += __shfl_down(s, o, 64);
  __shared__ float wsum[4];
  int lane = threadIdx.x & 63, w = threadIdx.x >> 6;
  if (!lane) wsum[w] = s;
  __syncthreads();
  if (threadIdx.x == 0) x0[id] = (wsum[0]+wsum[1]+wsum[2]+wsum[3]) * (1.f/3136.f);
}

// ---------------- K2: routing function (per-batch block) ----------------
__global__ __launch_bounds__(256) void k_route(
    const float* __restrict__ x0, const float* __restrict__ a_w, const float* __restrict__ a_b,
    const float* __restrict__ norm_w, const float* __restrict__ norm_b,
    const float* __restrict__ normt_w, const float* __restrict__ normt_b,
    const float* __restrict__ qkv_w, const float* __restrict__ qkv_b,
    const float* __restrict__ ao_w, const float* __restrict__ ao_b,
    const float* __restrict__ b_w, const float* __restrict__ bb_w,
    const float* __restrict__ bias_p,
    float* __restrict__ wa, float* __restrict__ bbt){
  __shared__ float x0l[2048];
  __shared__ float x1[512];
  __shared__ float x2[512];
  __shared__ float xn[512];
  __shared__ float qkvl[1536];
  __shared__ float att[64];
  __shared__ float ol[512];
  __shared__ float x3[512];
  __shared__ float mu8[8], rs8[8];
  int b = blockIdx.x, tid = threadIdx.x;

  for (int i = tid; i < 2048; i += 256) x0l[i] = x0[b*2048 + i];
  __syncthreads();

  // conv 'a': x1[cr,t]
  for (int o = tid; o < 512; o += 256){
    int cr = o >> 3, t = o & 7;
    float acc = a_b[cr];
    const float* aw = a_w + cr*768;
    const float* xc = x0l + t;
    for (int c = 0; c < 256; ++c){
      float s = aw[c*3+1] * xc[c*8];
      if (t > 0) s += aw[c*3]   * xc[c*8 - 1];
      if (t < 7) s += aw[c*3+2] * xc[c*8 + 1];
      acc += s;
    }
    x1[o] = acc;
  }
  __syncthreads();

  // LN over channels + qGELU
  if (tid < 8){
    float s = 0.f, q = 0.f;
    for (int cr = 0; cr < 64; ++cr){ float v = x1[cr*8 + tid]; s += v; q += v*v; }
    float mu = s * (1.f/64.f);
    float var = q * (1.f/64.f) - mu*mu;
    mu8[tid] = mu; rs8[tid] = rsqrtf(var + 1e-6f);
  }
  __syncthreads();
  for (int o = tid; o < 512; o += 256){
    int cr = o >> 3, t = o & 7;
    float v = (x1[o] - mu8[t]) * rs8[t] * norm_w[cr] + norm_b[cr];
    x2[o] = v * (1.f / (1.f + __expf(-1.702f * v)));
  }
  __syncthreads();

  // LN_t
  if (tid < 8){
    float s = 0.f, q = 0.f;
    for (int cr = 0; cr < 64; ++cr){ float v = x2[cr*8 + tid]; s += v; q += v*v; }
    float mu = s * (1.f/64.f);
    float var = q * (1.f/64.f) - mu*mu;
    mu8[tid] = mu; rs8[tid] = rsqrtf(var + 1e-6f);
  }
  __syncthreads();
  for (int o = tid; o < 512; o += 256){
    int cr = o >> 3, t = o & 7;
    xn[o] = (x2[o] - mu8[t]) * rs8[t] * normt_w[cr] + normt_b[cr];
  }
  __syncthreads();

  // qkv: [192,64] @ xn
  for (int o = tid; o < 1536; o += 256){
    int oc = o >> 3, t = o & 7;
    float acc = qkv_b[oc];
    const float* qw = qkv_w + oc*64;
    for (int c = 0; c < 64; ++c) acc += qw[c] * xn[c*8 + t];
    qkvl[o] = acc;
  }
  __syncthreads();

  // attention scores (1 head, t=8), scale = 64^-0.5 = 0.125
  if (tid < 64){
    int tq = tid >> 3, tk = tid & 7;
    float s = 0.f;
    for (int d = 0; d < 64; ++d) s += qkvl[d*8 + tq] * qkvl[(64+d)*8 + tk];
    att[tid] = s * 0.125f;
  }
  __syncthreads();
  if (tid < 8){
    float m = att[tid*8];
    for (int k = 1; k < 8; ++k) m = fmaxf(m, att[tid*8 + k]);
    float e[8]; float s = 0.f;
    for (int k = 0; k < 8; ++k){ e[k] = __expf(att[tid*8 + k] - m); s += e[k]; }
    float inv = 1.f / s;
    for (int k = 0; k < 8; ++k) att[tid*8 + k] = e[k] * inv;
  }
  __syncthreads();
  // o = attn @ v  -> ol[tq*64+d]
  for (int o = tid; o < 512; o += 256){
    int tq = o >> 6, d = o & 63;
    float acc = 0.f;
    for (int k = 0; k < 8; ++k) acc += att[tq*8 + k] * qkvl[(128+d)*8 + k];
    ol[o] = acc;
  }
  __syncthreads();
  // proj + residual
  for (int o = tid; o < 512; o += 256){
    int cr = o >> 3, t = o & 7;
    float acc = ao_b[cr];
    const float* aw = ao_w + cr*64;
    for (int d = 0; d < 64; ++d) acc += aw[d] * ol[t*64 + d];
    x3[o] = x2[o] + acc;
  }
  __syncthreads();
  // w_alpha / bias_bt
  for (int o = tid; o < 2048; o += 256){
    int c = o >> 3, t = o & 7;
    float wacc = 0.f, bacc = 0.f;
    const float* xc = x3 + t;
    const float* bw  = b_w  + c*192;
    const float* bw2 = bb_w + c*192;
    for (int cr = 0; cr < 64; ++cr){
      float xm = xc[cr*8];
      wacc += bw[cr*3+1]*xm;  bacc += bw2[cr*3+1]*xm;
      if (t > 0){ float xl = xc[cr*8-1]; wacc += bw[cr*3]*xl;   bacc += bw2[cr*3]*xl; }
      if (t < 7){ float xr = xc[cr*8+1]; wacc += bw[cr*3+2]*xr; bacc += bw2[cr*3+2]*xr; }
    }
    wa[b*2048 + o] = wacc;
    bbt[(b*8 + t)*256 + c] = bacc * bias_p[c];
  }
}

// ---------------- K2.5: materialize xs[bt][r 0..57][cc 0..57][ci 0..255] bf16 ----------------
// scaled by wa, zero-padded in r and cc, ci-fastest, bank-swizzle baked into layout:
//   byte(cc,ci) = cc*512 + (ci>>6)*128 + ( (ci&63)*2  ^  (((2*r+cc)&7)<<4) )
__global__ __launch_bounds__(256) void k_xs(const float* __restrict__ feat,
                                            const float* __restrict__ wa,
                                            short* __restrict__ xs){
  __shared__ short lbuf[14848];            // 29696 B = one row block
  int bid = blockIdx.x;                    // 64*58
  int img = bid / 58, r = bid - img*58;
  int b = img >> 3, t = img & 7;
  int tid = threadIdx.x;

  f32x4* l4 = (f32x4*)lbuf;
  for (int i = tid; i < 1856; i += 256) l4[i] = f32x4{0.f,0.f,0.f,0.f};
  __syncthreads();

  if (r > 0 && r < 57){
    int y = r - 1;
    int p = tid & 127, h = tid >> 7;       // ci-pair p, x-half h
    int ci = p*2;
    float s0 = wa[(b*256 + ci)*8 + t];
    float s1 = wa[(b*256 + ci + 1)*8 + t];
    const float* f0 = feat + (size_t)b*2048*3136 + (size_t)ci*CI_STRIDE + t*3136 + y*56 + h*28;
    const f32x4* F0 = (const f32x4*)f0;
    const f32x4* F1 = (const f32x4*)(f0 + CI_STRIDE);
    int c4off = (ci >> 6)*128;
    int w2 = (ci & 63)*2;
    #pragma unroll
    for (int j4 = 0; j4 < 7; ++j4){
      f32x4 a = F0[j4], c = F1[j4];
      #pragma unroll
      for (int e = 0; e < 4; ++e){
        int x = h*28 + j4*4 + e;
        int cc = x + 1;
        unsigned pk = pk2_bf16(a[e]*s0, c[e]*s1);
        int swz = ((2*r + cc) & 7) << 4;
        int addr = cc*512 + c4off + (w2 ^ swz);
        *(unsigned*)((char*)lbuf + addr) = pk;
      }
    }
  }
  __syncthreads();

  f32x4* dst = (f32x4*)(xs + (size_t)(img*58 + r)*14848);
  for (int i = tid; i < 1856; i += 256) dst[i] = l4[i];
}

// ---------------- K3 fast: calibrated 3x3 conv, linear global_load_lds staging ----------------
__global__ __launch_bounds__(256) void k_conv2(const short* __restrict__ xs,
                                               const short* __restrict__ Wb,
                                               const float* __restrict__ bbt,
                                               float* __restrict__ out){
  __shared__ short buf[2][14848];   // 29696 B each, swizzled [cc][ci] row blocks

  int bid = blockIdx.x;
  int swz = (bid & 7)*448 + (bid >> 3);   // bijective XCD swizzle (3584 = 8*448)
  int img = swz / 56, y = swz - img*56;
  int b = img >> 3, t = img & 7;
  int tid = threadIdx.x;
  int lane = tid & 63, wave = tid >> 6;
  int arow = lane & 15, agrp = lane >> 4;

  const short* src = xs + (size_t)img*58*14848;

  f32x4 acc[4][4] = {};

  auto stage = [&](int bi, int r){
    const char* g = (const char*)(src + (size_t)r*14848);
    char* l = (char*)&buf[bi][0];
    int base = wave*464;                 // 464 16-B chunks per wave (4*464=1856)
    for (int j = lane; j < 464; j += 64){
      int idx = base + j;
      GL2LDS16(g + idx*16, l + idx*16);
    }
  };

  auto compute = [&](int bi, int ky){
    const short* sb = buf[bi];
    int rr2 = (2*(y + ky)) & 7;          // (58*r)&7 == (2r)&7
    for (int kx = 0; kx < 3; ++kx){
      const short* wsl = Wb + (size_t)(ky*3 + kx)*65536 + (wave*64 + arow)*256;
      for (int cs = 0; cs < 8; ++cs){
        short8 af[4], bfr[4];
        #pragma unroll
        for (int cf = 0; cf < 4; ++cf)
          af[cf] = *(const short8*)(wsl + cf*4096 + cs*32 + agrp*8);
        int c4 = (cs >> 1)*128;
        int w2 = ((cs & 1) << 6) | (agrp << 4);
        #pragma unroll
        for (int pf = 0; pf < 4; ++pf){
          int cc = (pf << 4) + arow + kx;
          if (cc > 57) cc = 57;          // pf=3 tail lanes: junk, discarded in epilogue
          int addr = cc*512 + c4 + (w2 ^ (((rr2 + cc) & 7) << 4));
          bfr[pf] = *(const short8*)((const char*)sb + addr);
        }
        #pragma unroll
        for (int cf = 0; cf < 4; ++cf){
          #pragma unroll
          for (int pf = 0; pf < 4; ++pf)
            acc[cf][pf] = __builtin_amdgcn_mfma_f32_16x16x32_bf16(af[cf], bfr[pf], acc[cf][pf], 0, 0, 0);
        }
      }
    }
  };

  stage(0, y);        // rows r = y, y+1, y+2 (padded indices), always in [0,57]
  stage(1, y + 1);
  asm volatile("s_waitcnt vmcnt(0)" ::: "memory");
  __builtin_amdgcn_s_barrier();
  compute(0, 0);
  __syncthreads();                      // all waves done reading buf0; also drains everything
  stage(0, y + 2);                      // overlaps with compute(1)
  compute(1, 1);
  asm volatile("s_waitcnt vmcnt(0)" ::: "memory");
  __builtin_amdgcn_s_barrier();
  compute(0, 2);

  // epilogue: D[row][col]: col=lane&15 (x), row=(lane>>4)*4+reg (co)
  float* obase = out + (size_t)b*256*8*3136 + (size_t)t*3136 + y*56;
  const float* bb = bbt + (b*8 + t)*256;
  #pragma unroll
  for (int cf = 0; cf < 4; ++cf){
    int co0 = wave*64 + cf*16 + agrp*4;
    #pragma unroll
    for (int r = 0; r < 4; ++r){
      int co = co0 + r;
      float bias = bb[co];
      float* orow = obase + (size_t)co*CI_STRIDE;
      #pragma unroll
      for (int pf = 0; pf < 4; ++pf){
        int x = (pf << 4) + arow;
        if (x < 56) orow[x] = acc[cf][pf][r] + bias;
      }
    }
  }
}

// ---------------- K3 fallback: round-1 conv (used only if ws too small for xs) ----------------
__global__ __launch_bounds__(256) void k_conv_fb(const float* __restrict__ feat,
                                                 const short* __restrict__ Wb,
                                                 const float* __restrict__ wa,
                                                 const float* __restrict__ bbt,
                                                 float* __restrict__ out){
  __shared__ short buf[2][58*256];
  __shared__ float wal[256];

  int bid = blockIdx.x;
  int swz = (bid & 7)*448 + (bid >> 3);
  int img = swz / 56, y = swz - img*56;
  int b = img >> 3, t = img & 7;
  int tid = threadIdx.x;
  int lane = tid & 63, wave = tid >> 6;
  int arow = lane & 15, agrp = lane >> 4;

  wal[tid] = wa[(b*256 + tid)*8 + t];
  __syncthreads();

  const float* fb = feat + (size_t)b*256*8*3136 + (size_t)t*3136;
  f32x4 acc[4][4] = {};

  auto stage = [&](int bi, int ky){
    short* dst = buf[bi];
    int yin = y + ky - 1;
    bool rowok = (yin >= 0) && (yin < 56);
    const float* rsrc = fb + (size_t)yin*56;
    for (int i = tid; i < 128*58; i += 256){
      int ci2 = i / 58;
      int col = i - ci2*58;
      int ci = ci2 << 1;
      float v0 = 0.f, v1 = 0.f;
      int x = col - 1;
      if (rowok && (unsigned)x < 56u){
        v0 = rsrc[(size_t)ci*CI_STRIDE + x]     * wal[ci];
        v1 = rsrc[(size_t)(ci+1)*CI_STRIDE + x] * wal[ci+1];
      }
      unsigned p = pk2_bf16(v0, v1);
      int addr = ((col << 9) | (ci << 1)) ^ ((col & 7) << 4);
      *(unsigned*)((char*)dst + addr) = p;
    }
  };

  auto compute = [&](int bi, int ky){
    const short* sbuf = buf[bi];
    for (int kx = 0; kx < 3; ++kx){
      const short* wsl = Wb + (size_t)(ky*3 + kx)*65536 + (wave*64 + arow)*256 + (agrp << 3);
      for (int cs = 0; cs < 8; ++cs){
        int ci0 = (cs << 5) + (agrp << 3);
        short8 af[4], bfr[4];
        #pragma unroll
        for (int cf = 0; cf < 4; ++cf)
          af[cf] = *(const short8*)(wsl + cf*16*256 + (cs << 5));
        #pragma unroll
        for (int pf = 0; pf < 4; ++pf){
          int col = (pf << 4) + arow + kx;
          if (col > 57) col = 57;
          int addr = ((col << 9) | (ci0 << 1)) ^ ((col & 7) << 4);
          bfr[pf] = *(const short8*)((const char*)sbuf + addr);
        }
        #pragma unroll
        for (int cf = 0; cf < 4; ++cf){
          #pragma unroll
          for (int pf = 0; pf < 4; ++pf)
            acc[cf][pf] = __builtin_amdgcn_mfma_f32_16x16x32_bf16(af[cf], bfr[pf], acc[cf][pf], 0, 0, 0);
        }
      }
    }
  };

  stage(0, 0);
  __syncthreads();
  stage(1, 1);
  compute(0, 0);
  __syncthreads();
  stage(0, 2);
  compute(1, 1);
  __syncthreads();
  compute(0, 2);

  float* obase = out + (size_t)b*256*8*3136 + (size_t)t*3136 + y*56;
  const float* bb = bbt + (b*8 + t)*256;
  #pragma unroll
  for (int cf = 0; cf < 4; ++cf){
    int co0 = wave*64 + cf*16 + agrp*4;
    #pragma unroll
    for (int r = 0; r < 4; ++r){
      int co = co0 + r;
      float bias = bb[co];
      float* orow = obase + (size_t)co*CI_STRIDE;
      #pragma unroll
      for (int pf = 0; pf < 4; ++pf){
        int x = (pf << 4) + arow;
        if (x < 56) orow[x] = acc[cf][pf][r] + bias;
      }
    }
  }
}

// ---------------- K4: per-channel stats of out and its temporal 3-avgpool ----------------
__global__ __launch_bounds__(256) void k_stats(const float* __restrict__ out,
                                               float* __restrict__ stats){
  int bc = blockIdx.x;          // b*256 + c
  int c = bc & 255;
  const f32x4* base = (const f32x4*)(out + (size_t)bc*CI_STRIDE);
  float so = 0.f, ss = 0.f, sp = 0.f, sq = 0.f;
  const float inv3 = 1.f/3.f;
  for (int i = threadIdx.x; i < 784; i += 256){
    f32x4 v[8];
    #pragma unroll
    for (int t2 = 0; t2 < 8; ++t2) v[t2] = base[t2*784 + i];
    #pragma unroll
    for (int t2 = 0; t2 < 8; ++t2){
      f32x4 x = v[t2];
      so += (x.x + x.y) + (x.z + x.w);
      ss += (x.x*x.x + x.y*x.y) + (x.z*x.z + x.w*x.w);
    }
    #pragma unroll
    for (int t2 = 0; t2 < 8; ++t2){
      f32x4 s = v[t2];
      if (t2 > 0) s = s + v[t2-1];
      if (t2 < 7) s = s + v[t2+1];
      f32x4 a = s * inv3;
      sp += (a.x + a.y) + (a.z + a.w);
      sq += (a.x*a.x + a.y*a.y) + (a.z*a.z + a.w*a.w);
    }
  }
  for (int o = 32; o; o >>= 1){
    so += __shfl_down(so, o, 64); ss += __shfl_down(ss, o, 64);
    sp += __shfl_down(sp, o, 64); sq += __shfl_down(sq, o, 64);
  }
  __shared__ float red[4][4];
  int lane = threadIdx.x & 63, w = threadIdx.x >> 6;
  if (!lane){ red[w][0] = so; red[w][1] = ss; red[w][2] = sp; red[w][3] = sq; }
  __syncthreads();
  if (threadIdx.x < 4){
    float s = red[0][threadIdx.x] + red[1][threadIdx.x] + red[2][threadIdx.x] + red[3][threadIdx.x];
    atomicAdd(&stats[c*4 + threadIdx.x], s);
  }
}

// ---------------- K5: finalize per-channel BN scale/offset ----------------
__global__ void k_scale(const float* __restrict__ stats,
                        const float* __restrict__ ga, const float* __restrict__ ba_,
                        const float* __restrict__ gb, const float* __restrict__ bb_,
                        float* __restrict__ scale){
  int c = threadIdx.x;
  const float n = 200704.f;
  float mu_a = stats[c*4]   / n;
  float va   = stats[c*4+1] / n - mu_a*mu_a;
  float mu_p = stats[c*4+2] / n;
  float vp   = stats[c*4+3] / n - mu_p*mu_p;
  float ra = rsqrtf(va + 1e-5f) * ga[c];
  float rp = rsqrtf(vp + 1e-5f) * gb[c];
  scale[c*3]   = ra;
  scale[c*3+1] = rp;
  scale[c*3+2] = ba_[c] + bb_[c] - mu_a*ra - mu_p*rp;
}

// ---------------- K6: in-place normalize: out = bn_a(out) + bn_b(avgpool_t3(out)) ----------------
__global__ __launch_bounds__(256) void k_final(float* __restrict__ out,
                                               const float* __restrict__ scale){
  int bc = blockIdx.x;
  int c = bc & 255;
  float ra  = scale[c*3];
  float rp  = scale[c*3+1];
  float off = scale[c*3+2];
  f32x4* base = (f32x4*)(out + (size_t)bc*CI_STRIDE);
  const float inv3 = 1.f/3.f;
  for (int i = threadIdx.x; i < 784; i += 256){
    f32x4 v[8];
    #pragma unroll
    for (int t2 = 0; t2 < 8; ++t2) v[t2] = base[t2*784 + i];
    #pragma unroll
    for (int t2 = 0; t2 < 8; ++t2){
      f32x4 s = v[t2];
      if (t2 > 0) s = s + v[t2-1];
      if (t2 < 7) s = s + v[t2+1];
      f32x4 o = v[t2]*ra + (s*inv3)*rp + off;
      base[t2*784 + i] = o;
    }
  }
}

extern "C" void kernel_launch(void* const* d_in, const int* in_sizes, int n_in,
                              void* d_out, int out_size, void* d_ws, size_t ws_size,
                              hipStream_t stream){
  (void)in_sizes; (void)n_in; (void)out_size;
  const float* feat    = (const float*)d_in[0];
  const float* W       = (const float*)d_in[1];
  const float* bias_p  = (const float*)d_in[2];
  const float* a_w     = (const float*)d_in[3];
  const float* a_b     = (const float*)d_in[4];
  const float* norm_w  = (const float*)d_in[5];
  const float* norm_b  = (const float*)d_in[6];
  const float* normt_w = (const float*)d_in[7];
  const float* normt_b = (const float*)d_in[8];
  const float* qkv_w   = (const float*)d_in[9];
  const float* qkv_b   = (const float*)d_in[10];
  const float* ao_w    = (const float*)d_in[11];
  const float* ao_b    = (const float*)d_in[12];
  const float* b_w     = (const float*)d_in[13];
  const float* bb_w    = (const float*)d_in[14];
  const float* gamma_a = (const float*)d_in[15];
  const float* beta_a  = (const float*)d_in[16];
  const float* gamma_b = (const float*)d_in[17];
  const float* beta_b  = (const float*)d_in[18];
  float* out = (float*)d_out;

  char* ws = (char*)d_ws;
  short* Wb    = (short*)ws;                               // 1,179,648 B
  float* x0    = (float*)(ws + 1179648);                   // 65,536 B
  float* wa    = (float*)(ws + 1179648 + 65536);           // 65,536 B
  float* bbt   = (float*)(ws + 1179648 + 2*65536);         // 65,536 B
  float* stats = (float*)(ws + 1179648 + 3*65536);         // 4,096 B
  float* scale = (float*)(ws + 1179648 + 3*65536 + 4096);  // 3,072 B
  // xs: 64 * 58 * 29696 B = 110,231,552 at offset 1,383,424 (1KiB-aligned)
  short* xs    = (short*)(ws + 1383424);
  const size_t NEED = 1383424ull + 110231552ull;
  bool fast = ws_size >= NEED;

  k_prep <<<2304, 256, 0, stream>>>(W, Wb, stats);
  k_mean <<<16384, 256, 0, stream>>>(feat, x0);
  k_route<<<8, 256, 0, stream>>>(x0, a_w, a_b, norm_w, norm_b, normt_w, normt_b,
                                 qkv_w, qkv_b, ao_w, ao_b, b_w, bb_w, bias_p, wa, bbt);
  if (fast){
    k_xs   <<<3712, 256, 0, stream>>>(feat, wa, xs);
    k_conv2<<<3584, 256, 0, stream>>>(xs, Wb, bbt, out);
  } else {
    k_conv_fb<<<3584, 256, 0, stream>>>(feat, Wb, wa, bbt, out);
  }
  k_stats<<<2048, 256, 0, stream>>>(out, stats);
  k_scale<<<1, 256, 0, stream>>>(stats, gamma_a, beta_a, gamma_b, beta_b, scale);
  k_final<<<2048, 256, 0, stream>>>(out, scale);
}